// Round 10
// baseline (601.178 us; speedup 1.0000x reference)
//
#include <hip/hip_runtime.h>
#include <hip/hip_bf16.h>

typedef unsigned int u32;
typedef unsigned short u16;
typedef _Float16 f16;
typedef __attribute__((ext_vector_type(8))) f16 f16x8;
typedef __attribute__((ext_vector_type(8))) u16 u16x8;
typedef __attribute__((ext_vector_type(4))) float f32x4;
typedef __attribute__((ext_vector_type(4))) u16 u16x4;

#define NB 4096
#define DIN 10338
#define DPAD 10368
#define KC 5184            // G1 K half (162 * 32)
#define HD 1024
#define OD 226
#define OPAD 256
#define BN_EPS 1e-5f
#define RSC 0.00048828125f // 2^-11

__device__ __forceinline__ u16 f2h(float v) {
  f16 h = (f16)v;
  u16 r;
  __builtin_memcpy(&r, &h, 2);
  return r;
}
// 2-plane f16 split, residual plane pre-scaled by 2^11 (keeps it normal):
// a ~= h0 + h1 * 2^-11, dropped ~ 2^-22 * a
__device__ __forceinline__ void split2(float a, u16& s0, u16& s1) {
  f16 h0 = (f16)a;
  float r = (a - (float)h0) * 2048.0f;
  __builtin_memcpy(&s0, &h0, 2);
  s1 = f2h(r);
}

__device__ __forceinline__ void gload_lds16(const u16* g, u16* l) {
  __builtin_amdgcn_global_load_lds(
      (const __attribute__((address_space(1))) u32*)g,
      (__attribute__((address_space(3))) u32*)l, 16, 0, 0);
}

// ---- W f32 [K][N] -> 2 transposed f16 planes [Npad][Kp] (zero-padded)
__global__ __launch_bounds__(256) void k_split_w(const float* __restrict__ W,
                                                 f16* __restrict__ p0,
                                                 f16* __restrict__ p1, int K,
                                                 int N, int Kp) {
  __shared__ float tile[32][33];
  int k0 = blockIdx.x * 32, n0 = blockIdx.y * 32;
  int tx = threadIdx.x, ty = threadIdx.y;
#pragma unroll
  for (int i = 0; i < 4; i++) {
    int k = k0 + ty + i * 8, n = n0 + tx;
    tile[ty + i * 8][tx] = (k < K && n < N) ? W[(size_t)k * N + n] : 0.f;
  }
  __syncthreads();
#pragma unroll
  for (int i = 0; i < 4; i++) {
    int n = n0 + ty + i * 8, k = k0 + tx;
    u16 s0, s1;
    split2(tile[tx][ty + i * 8], s0, s1);
    size_t o = (size_t)n * Kp + k;
    ((u16*)p0)[o] = s0;
    ((u16*)p1)[o] = s1;
  }
}

// ---- batched variant: 4 HD x HD weights in one dispatch (blockIdx.z)
struct WPack {
  const float* W[4];
  f16* p0[4];
  f16* p1[4];
};
__global__ __launch_bounds__(256) void k_split_w4(WPack wp) {
  __shared__ float tile[32][33];
  const float* __restrict__ W = wp.W[blockIdx.z];
  f16* __restrict__ p0 = wp.p0[blockIdx.z];
  f16* __restrict__ p1 = wp.p1[blockIdx.z];
  int k0 = blockIdx.x * 32, n0 = blockIdx.y * 32;
  int tx = threadIdx.x, ty = threadIdx.y;
#pragma unroll
  for (int i = 0; i < 4; i++) {
    int k = k0 + ty + i * 8, n = n0 + tx;
    tile[ty + i * 8][tx] = W[(size_t)k * HD + n];
  }
  __syncthreads();
#pragma unroll
  for (int i = 0; i < 4; i++) {
    int n = n0 + ty + i * 8, k = k0 + tx;
    u16 s0, s1;
    split2(tile[tx][ty + i * 8], s0, s1);
    size_t o = (size_t)n * HD + k;
    ((u16*)p0)[o] = s0;
    ((u16*)p1)[o] = s1;
  }
}

// ==== G1 big-tile GEMM: BM=256 x BN=128, K-split-2 (blockIdx.z), 8 waves
// (4M x 2N, wave tile 64x64), BK=32, ring-3 LDS (144 KB), round-7 3-phase
// schedule. A is reg-staged from x (f32) with in-kernel split2 + swizzled
// ds_write. FIXED vs round-8: A loads issued BEFORE B each tile, phase-2
// waits vmcnt(2) (A landed, this tile's B pair stays in flight) — restores
// the r7 counted-vmcnt pipeline invariant.
// Buffers: A0 @0, A1 @8192, B0 @16384, B1 @20480 (u16 units).
__global__ __launch_bounds__(512, 2) void k_gemm_big(
    const float* __restrict__ X, const f16* __restrict__ B0p,
    const f16* __restrict__ B1p, float* __restrict__ P, int ldB, int nk) {
  __shared__ __align__(16) u16 lds[3 * 24576];

  const u32 gx = gridDim.x, gy = gridDim.y;
  const u32 nwg = gx * gy * gridDim.z;
  u32 lin = blockIdx.x + gx * (blockIdx.y + gy * blockIdx.z);
  {  // bijective XCD swizzle: the 8 bx-blocks of one (by,bz) share an XCD
    const u32 q = nwg >> 3, r = nwg & 7;
    const u32 xcd = lin & 7, o = lin >> 3;
    lin = (xcd < r ? xcd * (q + 1) : r * (q + 1) + (xcd - r) * q) + o;
  }
  const u32 bz = lin / (gx * gy);
  const u32 rem = lin - bz * gx * gy;
  const u32 by = rem / gx;
  const u32 bx = rem - by * gx;
  const int m0 = by * 256, n0 = bx * 128;
  const int kbase = (int)bz * KC;

  const u16* __restrict__ B0u = (const u16*)B0p + kbase;
  const u16* __restrict__ B1u = (const u16*)B1p + kbase;
  float* __restrict__ Pz = P + (size_t)bz * NB * HD;

  const int t = threadIdx.x;
  const int lane = t & 63;
  const int wid = t >> 6;
  const int wm = wid >> 1, wn = wid & 1;  // 4M x 2N waves, tile 64x64
  const int l15 = lane & 15, l4 = lane >> 4;

  // B staging (global_load_lds, pre-swizzled source): chunk c = t
  const int sgc = (((t & 3) ^ ((t >> 3) & 3)) << 3);
  const size_t gB = (size_t)(n0 + (t >> 2)) * ldB + sgc;
  const int dB = t * 8;

  // A reg-staging: thread covers row arow = t>>1, 16 cols at acol = (t&1)*16
  const int arow = t >> 1;
  const int acol = (t & 1) * 16;
  const float* __restrict__ xrow = X + (size_t)(m0 + arow) * DIN;
  const int swzA = (arow >> 1) & 3;
  const int wofA0 = arow * 32 + ((((acol >> 3) + 0) ^ swzA) << 3);
  const int wofA1 = arow * 32 + ((((acol >> 3) + 1) ^ swzA) << 3);

  // ds_read offsets (u16 units), same XOR swizzle
  int offA[4], offB[4];
#pragma unroll
  for (int mi = 0; mi < 4; mi++) {
    int row = wm * 64 + mi * 16 + l15;
    offA[mi] = row * 32 + ((l4 ^ ((row >> 1) & 3)) << 3);
  }
#pragma unroll
  for (int ni = 0; ni < 4; ni++) {
    int row = wn * 64 + ni * 16 + l15;
    offB[ni] = row * 32 + ((l4 ^ ((row >> 1) & 3)) << 3);
  }

  f32x4 hi[4][4], lo[4][4];
#pragma unroll
  for (int i = 0; i < 4; i++)
#pragma unroll
    for (int j = 0; j < 4; j++) {
      f32x4 z = {0.f, 0.f, 0.f, 0.f};
      hi[i][j] = z;
      lo[i][j] = z;
    }

  float2 av[8];  // in-flight A f32 values for tile tau+2

#define AREG_LOAD(klocal)                                            \
  {                                                                  \
    const int cg = kbase + (klocal) + acol;                          \
    if (cg + 16 <= DIN) {                                            \
      _Pragma("unroll") for (int j = 0; j < 8; j++)                  \
          av[j] = *(const float2*)(xrow + cg + 2 * j);               \
    } else {                                                         \
      _Pragma("unroll") for (int j = 0; j < 8; j++) {                \
        const int c = cg + 2 * j;                                    \
        av[j].x = (c < DIN) ? xrow[c] : 0.f;                         \
        av[j].y = (c + 1 < DIN) ? xrow[c + 1] : 0.f;                 \
      }                                                              \
    }                                                                \
  }

#define ASPLIT_WRITE(Sb)                                             \
  {                                                                  \
    u16x8 q0a, q0b, q1a, q1b;                                        \
    _Pragma("unroll") for (int j = 0; j < 4; j++) {                  \
      u16 s0x, s1x, s0y, s1y;                                        \
      split2(av[j].x, s0x, s1x);                                     \
      split2(av[j].y, s0y, s1y);                                     \
      q0a[2 * j] = s0x; q0a[2 * j + 1] = s0y;                        \
      q1a[2 * j] = s1x; q1a[2 * j + 1] = s1y;                        \
    }                                                                \
    _Pragma("unroll") for (int j = 0; j < 4; j++) {                  \
      u16 s0x, s1x, s0y, s1y;                                        \
      split2(av[4 + j].x, s0x, s1x);                                 \
      split2(av[4 + j].y, s0y, s1y);                                 \
      q0b[2 * j] = s0x; q0b[2 * j + 1] = s0y;                        \
      q1b[2 * j] = s1x; q1b[2 * j + 1] = s1y;                        \
    }                                                                \
    *(u16x8*)((Sb) + wofA0) = q0a;                                   \
    *(u16x8*)((Sb) + wofA1) = q0b;                                   \
    *(u16x8*)((Sb) + 8192 + wofA0) = q1a;                            \
    *(u16x8*)((Sb) + 8192 + wofA1) = q1b;                            \
  }

#define STAGE_B(Sb, ko)                               \
  gload_lds16(B0u + gB + (ko), (Sb) + 16384 + dB);    \
  gload_lds16(B1u + gB + (ko), (Sb) + 20480 + dB);

#define MFMA16(dst, af, bf)                                              \
  _Pragma("unroll") for (int mi = 0; mi < 4; mi++)                       \
      _Pragma("unroll") for (int ni = 0; ni < 4; ni++)                   \
          dst[mi][ni] = __builtin_amdgcn_mfma_f32_16x16x32_f16(          \
              af[mi], bf[ni], dst[mi][ni], 0, 0, 0);

  // prologue: A(0),A(1) via regs (drained), then B(0),B(1); end with
  // exactly B(1)'s 2 loads outstanding (steady-state invariant).
  AREG_LOAD(0)
  asm volatile("s_waitcnt vmcnt(0)" ::: "memory");
  ASPLIT_WRITE(lds)
  AREG_LOAD(32)
  asm volatile("s_waitcnt vmcnt(0)" ::: "memory");
  ASPLIT_WRITE(lds + 24576)
  STAGE_B(lds, 0)
  STAGE_B(lds + 24576, 32)
  asm volatile("s_waitcnt vmcnt(2)" ::: "memory");  // B(0) landed
  asm volatile("s_waitcnt lgkmcnt(0)" ::: "memory");
  __builtin_amdgcn_s_barrier();
  __builtin_amdgcn_sched_barrier(0);

  for (int tau = 0; tau < nk - 2; ++tau) {
    const u16* Lb = lds + (tau % 3) * 24576;
    u16* Sb = lds + ((tau + 2) % 3) * 24576;
    const int ko = (tau + 2) * 32;
    f16x8 a0[4], b0[4], xf[4];

    // issue next-next tile loads: A -> regs FIRST, then B -> LDS (DMA)
    AREG_LOAD(ko)
    STAGE_B(Sb, (size_t)ko)

    // ---- phase 0: read a0,b0; hi += a0*b0
#pragma unroll
    for (int mi = 0; mi < 4; mi++) a0[mi] = *(const f16x8*)(Lb + offA[mi]);
#pragma unroll
    for (int ni = 0; ni < 4; ni++)
      b0[ni] = *(const f16x8*)(Lb + 16384 + offB[ni]);
    __builtin_amdgcn_s_barrier();
    asm volatile("s_waitcnt lgkmcnt(0)" ::: "memory");
    __builtin_amdgcn_sched_barrier(0);
    __builtin_amdgcn_s_setprio(1);
    MFMA16(hi, a0, b0)
    __builtin_amdgcn_s_setprio(0);
    __builtin_amdgcn_s_barrier();

    // ---- phase 1: read b1; lo += a0*b1
#pragma unroll
    for (int ni = 0; ni < 4; ni++)
      xf[ni] = *(const f16x8*)(Lb + 20480 + offB[ni]);
    __builtin_amdgcn_s_barrier();
    asm volatile("s_waitcnt lgkmcnt(0)" ::: "memory");
    __builtin_amdgcn_sched_barrier(0);
    __builtin_amdgcn_s_setprio(1);
    MFMA16(lo, a0, xf)
    __builtin_amdgcn_s_setprio(0);
    __builtin_amdgcn_s_barrier();

    // ---- phase 2: read a1; vmcnt(2) retires B(tau+1)+A(tau+2), leaves
    //      B(tau+2) in flight; split+write A(tau+2); lo += a1*b0
#pragma unroll
    for (int mi = 0; mi < 4; mi++)
      xf[mi] = *(const f16x8*)(Lb + 8192 + offA[mi]);
    asm volatile("s_waitcnt vmcnt(2)" ::: "memory");
    ASPLIT_WRITE(Sb)
    __builtin_amdgcn_s_barrier();
    asm volatile("s_waitcnt lgkmcnt(0)" ::: "memory");
    __builtin_amdgcn_sched_barrier(0);
    __builtin_amdgcn_s_setprio(1);
    MFMA16(lo, xf, b0)
    __builtin_amdgcn_s_setprio(0);
    __builtin_amdgcn_s_barrier();
  }
  // tail: drain remaining B, then compute last 2 tiles (all resident)
  asm volatile("s_waitcnt vmcnt(0)" ::: "memory");
  asm volatile("s_waitcnt lgkmcnt(0)" ::: "memory");
  __builtin_amdgcn_s_barrier();
  __builtin_amdgcn_sched_barrier(0);
#pragma unroll 1
  for (int tau = nk - 2; tau < nk; ++tau) {
    const u16* Lb = lds + (tau % 3) * 24576;
    f16x8 a0[4], b0[4], xf[4];
#pragma unroll
    for (int mi = 0; mi < 4; mi++) a0[mi] = *(const f16x8*)(Lb + offA[mi]);
#pragma unroll
    for (int ni = 0; ni < 4; ni++)
      b0[ni] = *(const f16x8*)(Lb + 16384 + offB[ni]);
    MFMA16(hi, a0, b0)
#pragma unroll
    for (int ni = 0; ni < 4; ni++)
      xf[ni] = *(const f16x8*)(Lb + 20480 + offB[ni]);
    MFMA16(lo, a0, xf)
#pragma unroll
    for (int mi = 0; mi < 4; mi++)
      xf[mi] = *(const f16x8*)(Lb + 8192 + offA[mi]);
    MFMA16(lo, xf, b0)
  }
#undef AREG_LOAD
#undef ASPLIT_WRITE
#undef STAGE_B
#undef MFMA16

  // write raw f32 combined partials to this half's P
  const int rowb = m0 + wm * 64 + l4 * 4;
  const int colb = n0 + wn * 64 + l15;
#pragma unroll
  for (int mi = 0; mi < 4; mi++) {
#pragma unroll
    for (int ni = 0; ni < 4; ni++) {
      const int col = colb + ni * 16;
#pragma unroll
      for (int r = 0; r < 4; r++) {
        const int row = rowb + mi * 16 + r;
        Pz[(size_t)row * HD + col] = hi[mi][ni][r] + lo[mi][ni][r] * RSC;
      }
    }
  }
}

// ---- G1 epilogue: y = P0 + P1, BN + ReLU -> hF + f16 planes
__global__ __launch_bounds__(256) void k_epi1(
    const float* __restrict__ P0, const float* __restrict__ P1,
    const float* __restrict__ bias, const float* __restrict__ gam,
    const float* __restrict__ bet, const float* __restrict__ mu,
    const float* __restrict__ var, float* __restrict__ hF,
    f16* __restrict__ h0, f16* __restrict__ h1) {
  const u32 i4 = (blockIdx.x * 256u + threadIdx.x) * 4u;
  const u32 col0 = i4 & (HD - 1);
  f32x4 a = *(const f32x4*)(P0 + i4);
  f32x4 b = *(const f32x4*)(P1 + i4);
  f32x4 y;
  u16x4 o0, o1;
#pragma unroll
  for (int e = 0; e < 4; e++) {
    const u32 c = col0 + e;
    float sc = gam[c] * rsqrtf(var[c] + BN_EPS);
    float v = ((a[e] + b[e]) + bias[c] - mu[c]) * sc + bet[c];
    v = fmaxf(v, 0.f);
    y[e] = v;
    u16 s0, s1;
    split2(v, s0, s1);
    o0[e] = s0;
    o1[e] = s1;
  }
  *(f32x4*)(hF + i4) = y;
  *(u16x4*)((u16*)h0 + i4) = o0;
  *(u16x4*)((u16*)h1 + i4) = o1;
}

// ==== fused 128x128 GEMM (mids/G6): round-7 3-phase discipline, 8 waves
// (4M x 2N, wave tile 32x64), BK=32, ring-4 LDS, counted vmcnt(8), T2, T5.
// Buffer layout: A0 @0, A1 @4096, B0 @8192, B1 @12288.
// EPI: 1=mid(BN,ReLU -> planes) 2=res(BN,ReLU,+hF -> hF+planes)
//      3=res(-> planes only) 4=out(bias -> oF)
template <int EPI>
__global__ __launch_bounds__(512, 2) void k_gemm_f(
    const f16* __restrict__ A0p, const f16* __restrict__ A1p,
    const f16* __restrict__ B0p, const f16* __restrict__ B1p,
    const float* __restrict__ bias, const float* __restrict__ gam,
    const float* __restrict__ bet, const float* __restrict__ mu,
    const float* __restrict__ var, const float* __restrict__ resF,
    float* __restrict__ hFout, f16* __restrict__ pl0, f16* __restrict__ pl1,
    float* __restrict__ oF, int ldA, int ldB, int nk, int ldout) {
  __shared__ __align__(16) u16 lds[4 * 16384];

  const u32 gx = gridDim.x, gy = gridDim.y;
  const u32 nwg = gx * gy;
  u32 lin = blockIdx.x + gx * blockIdx.y;
  {
    const u32 q = nwg >> 3, r = nwg & 7;
    const u32 xcd = lin & 7, o = lin >> 3;
    lin = (xcd < r ? xcd * (q + 1) : r * (q + 1) + (xcd - r) * q) + o;
  }
  const u32 by = lin / gx;
  const u32 bx = lin - by * gx;
  const int m0 = by * 128, n0 = bx * 128;

  const u16* __restrict__ A0u = (const u16*)A0p;
  const u16* __restrict__ A1u = (const u16*)A1p;
  const u16* __restrict__ B0u = (const u16*)B0p;
  const u16* __restrict__ B1u = (const u16*)B1p;

  const int t = threadIdx.x;
  const int lane = t & 63;
  const int wid = t >> 6;
  const int wm = wid >> 1, wn = wid & 1;  // 4M x 2N, wave tile 32x64
  const int l15 = lane & 15, l4 = lane >> 4;

  const int srow = t >> 2, sj = t & 3;
  const int sgc = ((sj ^ ((srow >> 1) & 3)) << 3);
  const size_t gA = (size_t)(m0 + srow) * ldA + sgc;
  const size_t gB = (size_t)(n0 + srow) * ldB + sgc;
  const int d0 = t * 8;

  int offA[2], offB[4];
#pragma unroll
  for (int mi = 0; mi < 2; mi++) {
    int row = wm * 32 + mi * 16 + l15;
    offA[mi] = row * 32 + ((l4 ^ ((row >> 1) & 3)) << 3);
  }
#pragma unroll
  for (int ni = 0; ni < 4; ni++) {
    int row = wn * 64 + ni * 16 + l15;
    offB[ni] = row * 32 + ((l4 ^ ((row >> 1) & 3)) << 3);
  }

  f32x4 hi[2][4], lo[2][4];
#pragma unroll
  for (int i = 0; i < 2; i++)
#pragma unroll
    for (int j = 0; j < 4; j++) {
      f32x4 z = {0.f, 0.f, 0.f, 0.f};
      hi[i][j] = z;
      lo[i][j] = z;
    }

#define STG_A0(Sb, ko) gload_lds16(A0u + gA + (ko), (Sb) + d0);
#define STG_A1(Sb, ko) gload_lds16(A1u + gA + (ko), (Sb) + 4096 + d0);
#define STG_B(Sb, ko)                               \
  gload_lds16(B0u + gB + (ko), (Sb) + 8192 + d0);   \
  gload_lds16(B1u + gB + (ko), (Sb) + 12288 + d0);
#define MFMA8(dst, af, bf)                                               \
  _Pragma("unroll") for (int mi = 0; mi < 2; mi++)                       \
      _Pragma("unroll") for (int ni = 0; ni < 4; ni++)                   \
          dst[mi][ni] = __builtin_amdgcn_mfma_f32_16x16x32_f16(          \
              af[mi], bf[ni], dst[mi][ni], 0, 0, 0);

  // prologue: stage tiles 0,1,2 -> bufs 0,1,2
  {
    u16* S0 = lds;
    u16* S1 = lds + 16384;
    u16* S2 = lds + 32768;
    STG_A0(S0, 0) STG_A1(S0, 0) STG_B(S0, 0)
    STG_A0(S1, 32) STG_A1(S1, 32) STG_B(S1, 32)
    STG_A0(S2, 64) STG_A1(S2, 64) STG_B(S2, 64)
  }
  asm volatile("s_waitcnt vmcnt(8)" ::: "memory");
  __builtin_amdgcn_s_barrier();
  __builtin_amdgcn_sched_barrier(0);

  for (int tau = 0; tau < nk - 3; ++tau) {
    const u16* Lb = lds + (tau & 3) * 16384;
    u16* Sb = lds + ((tau + 3) & 3) * 16384;
    const size_t ko = (size_t)(tau + 3) * 32;
    f16x8 a0[2], b0[4], xf[4];

    // phase 0: read a0,b0; stage A0; hi += a0*b0
#pragma unroll
    for (int mi = 0; mi < 2; mi++) a0[mi] = *(const f16x8*)(Lb + offA[mi]);
#pragma unroll
    for (int ni = 0; ni < 4; ni++)
      b0[ni] = *(const f16x8*)(Lb + 8192 + offB[ni]);
    STG_A0(Sb, ko)
    __builtin_amdgcn_s_barrier();
    asm volatile("s_waitcnt lgkmcnt(0)" ::: "memory");
    __builtin_amdgcn_sched_barrier(0);
    __builtin_amdgcn_s_setprio(1);
    MFMA8(hi, a0, b0)
    __builtin_amdgcn_s_setprio(0);
    __builtin_amdgcn_s_barrier();

    // phase 1: read b1; stage A1; lo += a0*b1
#pragma unroll
    for (int ni = 0; ni < 4; ni++)
      xf[ni] = *(const f16x8*)(Lb + 12288 + offB[ni]);
    STG_A1(Sb, ko)
    __builtin_amdgcn_s_barrier();
    asm volatile("s_waitcnt lgkmcnt(0)" ::: "memory");
    __builtin_amdgcn_sched_barrier(0);
    __builtin_amdgcn_s_setprio(1);
    MFMA8(lo, a0, xf)
    __builtin_amdgcn_s_setprio(0);
    __builtin_amdgcn_s_barrier();

    // phase 2: read a1; stage B; vmcnt; lo += a1*b0
#pragma unroll
    for (int mi = 0; mi < 2; mi++)
      xf[mi] = *(const f16x8*)(Lb + 4096 + offA[mi]);
    STG_B(Sb, ko)
    asm volatile("s_waitcnt vmcnt(8)" ::: "memory");
    __builtin_amdgcn_s_barrier();
    asm volatile("s_waitcnt lgkmcnt(0)" ::: "memory");
    __builtin_amdgcn_sched_barrier(0);
    __builtin_amdgcn_s_setprio(1);
    MFMA8(lo, xf, b0)
    __builtin_amdgcn_s_setprio(0);
    __builtin_amdgcn_s_barrier();
  }
  asm volatile("s_waitcnt vmcnt(0)" ::: "memory");
  __builtin_amdgcn_s_barrier();
  __builtin_amdgcn_sched_barrier(0);
#pragma unroll 1
  for (int tau = nk - 3; tau < nk; ++tau) {
    const u16* Lb = lds + (tau & 3) * 16384;
    f16x8 a0[2], b0[4], xf[4];
#pragma unroll
    for (int mi = 0; mi < 2; mi++) a0[mi] = *(const f16x8*)(Lb + offA[mi]);
#pragma unroll
    for (int ni = 0; ni < 4; ni++)
      b0[ni] = *(const f16x8*)(Lb + 8192 + offB[ni]);
    MFMA8(hi, a0, b0)
#pragma unroll
    for (int ni = 0; ni < 4; ni++)
      xf[ni] = *(const f16x8*)(Lb + 12288 + offB[ni]);
    MFMA8(lo, a0, xf)
#pragma unroll
    for (int mi = 0; mi < 2; mi++)
      xf[mi] = *(const f16x8*)(Lb + 4096 + offA[mi]);
    MFMA8(lo, xf, b0)
  }
#undef STG_A0
#undef STG_A1
#undef STG_B
#undef MFMA8

  const int rowb = m0 + wm * 32 + l4 * 4;
  const int colb = n0 + wn * 64 + l15;
#pragma unroll
  for (int ni = 0; ni < 4; ni++) {
    const int col = colb + ni * 16;
    float sc = 1.f, pb = 0.f;
    if (EPI == 4) {
      pb = (col < OD) ? bias[col] : 0.f;
    } else {
      sc = gam[col] * rsqrtf(var[col] + BN_EPS);
      pb = (bias[col] - mu[col]) * sc + bet[col];
    }
#pragma unroll
    for (int mi = 0; mi < 2; mi++) {
#pragma unroll
      for (int r = 0; r < 4; r++) {
        const int row = rowb + mi * 16 + r;
        float s = hi[mi][ni][r] + lo[mi][ni][r] * RSC;
        if (EPI == 4) {
          oF[(size_t)row * ldout + col] = s + pb;
          continue;
        }
        float v = s * sc + pb;
        if (EPI == 2 || EPI == 3) v += resF[(size_t)row * HD + col];
        v = fmaxf(v, 0.f);
        if (EPI == 2) hFout[(size_t)row * HD + col] = v;
        u16 s0, s1;
        split2(v, s0, s1);
        size_t o = (size_t)row * HD + col;
        ((u16*)pl0)[o] = s0;
        ((u16*)pl1)[o] = s1;
      }
    }
  }
}

// ---- polar factor of each 3x3 block (scaled Newton) * sign(det); oF ld=256
__global__ __launch_bounds__(256) void k_polar(const float* __restrict__ oF,
                                               float* __restrict__ R) {
  int g = blockIdx.x * 256 + threadIdx.x;
  if (g >= NB * 24) return;
  int b = g / 24, j = g - b * 24;
  const float* p = oF + (size_t)b * OPAD + j * 9;
  float xv[9];
#pragma unroll
  for (int e = 0; e < 9; e++) xv[e] = p[e];
#pragma unroll 1
  for (int it = 0; it < 18; it++) {
    float c0 = xv[4] * xv[8] - xv[5] * xv[7];
    float c1 = xv[5] * xv[6] - xv[3] * xv[8];
    float c2 = xv[3] * xv[7] - xv[4] * xv[6];
    float c3 = xv[2] * xv[7] - xv[1] * xv[8];
    float c4 = xv[0] * xv[8] - xv[2] * xv[6];
    float c5 = xv[1] * xv[6] - xv[0] * xv[7];
    float c6 = xv[1] * xv[5] - xv[2] * xv[4];
    float c7 = xv[2] * xv[3] - xv[0] * xv[5];
    float c8 = xv[0] * xv[4] - xv[1] * xv[3];
    float det = xv[0] * c0 + xv[1] * c1 + xv[2] * c2;
    if (fabsf(det) < 1e-30f) break;
    float inv = 1.f / det;
    float y0 = c0 * inv, y1 = c1 * inv, y2 = c2 * inv;
    float y3 = c3 * inv, y4 = c4 * inv, y5 = c5 * inv;
    float y6 = c6 * inv, y7 = c7 * inv, y8 = c8 * inv;
    float gmm = 1.f;
    if (it < 8) {
      float nx = xv[0]*xv[0]+xv[1]*xv[1]+xv[2]*xv[2]+xv[3]*xv[3]+xv[4]*xv[4]
               + xv[5]*xv[5]+xv[6]*xv[6]+xv[7]*xv[7]+xv[8]*xv[8];
      float ny = y0*y0+y1*y1+y2*y2+y3*y3+y4*y4+y5*y5+y6*y6+y7*y7+y8*y8;
      gmm = sqrtf(sqrtf(ny / nx));
    }
    float a0 = 0.5f * gmm, a1 = 0.5f / gmm;
    xv[0] = a0 * xv[0] + a1 * y0; xv[1] = a0 * xv[1] + a1 * y1;
    xv[2] = a0 * xv[2] + a1 * y2; xv[3] = a0 * xv[3] + a1 * y3;
    xv[4] = a0 * xv[4] + a1 * y4; xv[5] = a0 * xv[5] + a1 * y5;
    xv[6] = a0 * xv[6] + a1 * y6; xv[7] = a0 * xv[7] + a1 * y7;
    xv[8] = a0 * xv[8] + a1 * y8;
  }
  float dfin = xv[0] * (xv[4] * xv[8] - xv[5] * xv[7])
             + xv[1] * (xv[5] * xv[6] - xv[3] * xv[8])
             + xv[2] * (xv[3] * xv[7] - xv[4] * xv[6]);
  float s = (dfin > 0.f) ? 1.f : -1.f;
  float* q = R + (size_t)g * 9;
#pragma unroll
  for (int e = 0; e < 9; e++) q[e] = s * xv[e];
}

__global__ __launch_bounds__(256) void k_betas(const float* __restrict__ oF,
                                               float* __restrict__ dst) {
  int i = blockIdx.x * 256 + threadIdx.x;
  if (i >= NB * 10) return;
  int b = i / 10, j = i - b * 10;
  dst[i] = oF[(size_t)b * OPAD + 216 + j];
}

extern "C" void kernel_launch(void* const* d_in, const int* in_sizes, int n_in,
                              void* d_out, int out_size, void* d_ws, size_t ws_size,
                              hipStream_t stream) {
  const float* x   = (const float*)d_in[0];
  const float* W1  = (const float*)d_in[1];
  const float* b1  = (const float*)d_in[2];
  const float* g1  = (const float*)d_in[3];
  const float* be1 = (const float*)d_in[4];
  const float* m1  = (const float*)d_in[5];
  const float* v1  = (const float*)d_in[6];
  const float* Wa  = (const float*)d_in[7];
  const float* ba  = (const float*)d_in[8];
  const float* ga  = (const float*)d_in[9];
  const float* bea = (const float*)d_in[10];
  const float* ma  = (const float*)d_in[11];
  const float* va  = (const float*)d_in[12];
  const float* Wb  = (const float*)d_in[13];
  const float* bb  = (const float*)d_in[14];
  const float* gb  = (const float*)d_in[15];
  const float* beb = (const float*)d_in[16];
  const float* mb  = (const float*)d_in[17];
  const float* vb  = (const float*)d_in[18];
  const float* Wc  = (const float*)d_in[19];
  const float* bc  = (const float*)d_in[20];
  const float* gc  = (const float*)d_in[21];
  const float* bec = (const float*)d_in[22];
  const float* mc  = (const float*)d_in[23];
  const float* vc  = (const float*)d_in[24];
  const float* Wd  = (const float*)d_in[25];
  const float* bd  = (const float*)d_in[26];
  const float* gd  = (const float*)d_in[27];
  const float* bed = (const float*)d_in[28];
  const float* md  = (const float*)d_in[29];
  const float* vd  = (const float*)d_in[30];
  const float* Wf  = (const float*)d_in[31];
  const float* bf  = (const float*)d_in[32];
  (void)in_sizes; (void)n_in; (void)out_size; (void)ws_size;

  char* ws = (char*)d_ws;
  size_t off = 0;
  auto alloc = [&](size_t bytes) -> void* {
    void* p = ws + off;
    off += (bytes + 255) & ~(size_t)255;
    return p;
  };
  f16* w1p0 = (f16*)alloc((size_t)HD * DPAD * 2);       // 21.2 MB
  f16* w1p1 = (f16*)alloc((size_t)HD * DPAD * 2);
  f16* wap0 = (f16*)alloc((size_t)HD * HD * 2);
  f16* wap1 = (f16*)alloc((size_t)HD * HD * 2);
  f16* wbp0 = (f16*)alloc((size_t)HD * HD * 2);
  f16* wbp1 = (f16*)alloc((size_t)HD * HD * 2);
  f16* wcp0 = (f16*)alloc((size_t)HD * HD * 2);
  f16* wcp1 = (f16*)alloc((size_t)HD * HD * 2);
  f16* wdp0 = (f16*)alloc((size_t)HD * HD * 2);
  f16* wdp1 = (f16*)alloc((size_t)HD * HD * 2);
  f16* wfp0 = (f16*)alloc((size_t)OPAD * HD * 2);
  f16* wfp1 = (f16*)alloc((size_t)OPAD * HD * 2);
  float* P = (float*)alloc((size_t)2 * NB * HD * 4);    // 33.6 MB (2 halves)
  f16* h0 = (f16*)alloc((size_t)NB * HD * 2);
  f16* h1 = (f16*)alloc((size_t)NB * HD * 2);
  f16* t0 = (f16*)alloc((size_t)NB * HD * 2);
  f16* t1 = (f16*)alloc((size_t)NB * HD * 2);
  float* hF = (float*)alloc((size_t)NB * HD * 4);
  float* oF = (float*)alloc((size_t)NB * OPAD * 4);     // total ~145 MB

  dim3 tb(32, 8);
  k_split_w<<<dim3(DPAD / 32, HD / 32), tb, 0, stream>>>(W1, w1p0, w1p1, DIN, HD, DPAD);
  WPack wp;
  wp.W[0] = Wa; wp.W[1] = Wb; wp.W[2] = Wc; wp.W[3] = Wd;
  wp.p0[0] = wap0; wp.p0[1] = wbp0; wp.p0[2] = wcp0; wp.p0[3] = wdp0;
  wp.p1[0] = wap1; wp.p1[1] = wbp1; wp.p1[2] = wcp1; wp.p1[3] = wdp1;
  k_split_w4<<<dim3(HD / 32, HD / 32, 4), tb, 0, stream>>>(wp);
  k_split_w<<<dim3(HD / 32, OPAD / 32), tb, 0, stream>>>(Wf, wfp0, wfp1, HD, OD, HD);

  dim3 g1g(HD / 128, NB / 256, 2);  // (8, 16, 2) = 256 blocks
  dim3 gg(HD / 128, NB / 128);      // (8, 32) = 256 blocks
  dim3 gf(OPAD / 128, NB / 128);    // (2, 32) = 64 blocks

  // G1 GEMM: reads x f32 directly (reg-staged split), K-split halves -> P0,P1
  k_gemm_big<<<g1g, 512, 0, stream>>>(x, w1p0, w1p1, P, DPAD, KC / 32);
  // G1 epilogue: h = relu(bn(P0+P1+b1)) -> hF + h planes
  k_epi1<<<NB * HD / 4 / 256, 256, 0, stream>>>(P, P + (size_t)NB * HD, b1, g1,
                                                be1, m1, v1, hF, h0, h1);
  // G2: t = relu(bn(h@Wa+ba)) -> t planes
  k_gemm_f<1><<<gg, 512, 0, stream>>>(
      h0, h1, wap0, wap1, ba, ga, bea, ma, va, nullptr, nullptr, t0, t1,
      nullptr, HD, HD, HD / 32, HD);
  // G3: h = relu(h + bn(t@Wb+bb)) -> hF + h planes (in-place hF safe)
  k_gemm_f<2><<<gg, 512, 0, stream>>>(
      t0, t1, wbp0, wbp1, bb, gb, beb, mb, vb, hF, hF, h0, h1, nullptr, HD,
      HD, HD / 32, HD);
  // G4: t = relu(bn(h@Wc+bc)) -> t planes
  k_gemm_f<1><<<gg, 512, 0, stream>>>(
      h0, h1, wcp0, wcp1, bc, gc, bec, mc, vc, nullptr, nullptr, t0, t1,
      nullptr, HD, HD, HD / 32, HD);
  // G5: h = relu(h + bn(t@Wd+bd)) -> h planes only
  k_gemm_f<3><<<gg, 512, 0, stream>>>(
      t0, t1, wdp0, wdp1, bd, gd, bed, md, vd, hF, nullptr, h0, h1, nullptr,
      HD, HD, HD / 32, HD);
  // G6: out = h@Wf+bf -> oF f32 [4096][256]
  k_gemm_f<4><<<gf, 512, 0, stream>>>(
      h0, h1, wfp0, wfp1, bf, nullptr, nullptr, nullptr, nullptr, nullptr,
      nullptr, nullptr, nullptr, oF, HD, HD, HD / 32, OPAD);

  float* Rout = (float*)d_out;
  k_polar<<<(NB * 24 + 255) / 256, 256, 0, stream>>>(oF, Rout);
  k_betas<<<(NB * 10 + 255) / 256, 256, 0, stream>>>(oF, Rout + (size_t)NB * 216);
}

// Round 11
// 510.673 us; speedup vs baseline: 1.1772x; 1.1772x over previous
//
#include <hip/hip_runtime.h>
#include <hip/hip_bf16.h>

typedef unsigned int u32;
typedef unsigned short u16;
typedef _Float16 f16;
typedef __attribute__((ext_vector_type(8))) f16 f16x8;
typedef __attribute__((ext_vector_type(4))) float f32x4;
typedef __attribute__((ext_vector_type(4))) u16 u16x4;

#define NB 4096
#define DIN 10338
#define DPAD 10368
#define KC 5184            // G1 K half (162 * 32)
#define HD 1024
#define OD 226
#define OPAD 256
#define BN_EPS 1e-5f
#define RSC 0.00048828125f // 2^-11

__device__ __forceinline__ u16 f2h(float v) {
  f16 h = (f16)v;
  u16 r;
  __builtin_memcpy(&r, &h, 2);
  return r;
}
// 2-plane f16 split, residual plane pre-scaled by 2^11 (keeps it normal):
// a ~= h0 + h1 * 2^-11, dropped ~ 2^-22 * a
__device__ __forceinline__ void split2(float a, u16& s0, u16& s1) {
  f16 h0 = (f16)a;
  float r = (a - (float)h0) * 2048.0f;
  __builtin_memcpy(&s0, &h0, 2);
  s1 = f2h(r);
}

__device__ __forceinline__ void gload_lds16(const u16* g, u16* l) {
  __builtin_amdgcn_global_load_lds(
      (const __attribute__((address_space(1))) u32*)g,
      (__attribute__((address_space(3))) u32*)l, 16, 0, 0);
}

// ---- x f32 [4096][10338] -> 2 f16 planes [4096][10368] (zero-padded)
__global__ __launch_bounds__(256) void k_split_x(const float* __restrict__ x,
                                                 f16* __restrict__ p0,
                                                 f16* __restrict__ p1) {
  u32 idx = (blockIdx.x * 256u + threadIdx.x) * 4u;  // [0, NB*DPAD)
  u32 row = idx / DPAD;
  u32 col = idx - row * DPAD;
  const float* s = x + (size_t)row * DIN + col;
  float v[4];
#pragma unroll
  for (int i = 0; i < 4; i++) {
    v[i] = ((int)col + i < DIN) ? s[i] : 0.f;
  }
  u16x4 o0, o1;
#pragma unroll
  for (int i = 0; i < 4; i++) {
    u16 a0, a1;
    split2(v[i], a0, a1);
    o0[i] = a0;
    o1[i] = a1;
  }
  *(u16x4*)((u16*)p0 + idx) = o0;
  *(u16x4*)((u16*)p1 + idx) = o1;
}

// ---- W f32 [K][N] -> 2 transposed f16 planes [Npad][Kp] (zero-padded)
__global__ __launch_bounds__(256) void k_split_w(const float* __restrict__ W,
                                                 f16* __restrict__ p0,
                                                 f16* __restrict__ p1, int K,
                                                 int N, int Kp) {
  __shared__ float tile[32][33];
  int k0 = blockIdx.x * 32, n0 = blockIdx.y * 32;
  int tx = threadIdx.x, ty = threadIdx.y;
#pragma unroll
  for (int i = 0; i < 4; i++) {
    int k = k0 + ty + i * 8, n = n0 + tx;
    tile[ty + i * 8][tx] = (k < K && n < N) ? W[(size_t)k * N + n] : 0.f;
  }
  __syncthreads();
#pragma unroll
  for (int i = 0; i < 4; i++) {
    int n = n0 + ty + i * 8, k = k0 + tx;
    u16 s0, s1;
    split2(tile[tx][ty + i * 8], s0, s1);
    size_t o = (size_t)n * Kp + k;
    ((u16*)p0)[o] = s0;
    ((u16*)p1)[o] = s1;
  }
}

// ---- batched variant: 4 HD x HD weights in one dispatch (blockIdx.z)
struct WPack {
  const float* W[4];
  f16* p0[4];
  f16* p1[4];
};
__global__ __launch_bounds__(256) void k_split_w4(WPack wp) {
  __shared__ float tile[32][33];
  const float* __restrict__ W = wp.W[blockIdx.z];
  f16* __restrict__ p0 = wp.p0[blockIdx.z];
  f16* __restrict__ p1 = wp.p1[blockIdx.z];
  int k0 = blockIdx.x * 32, n0 = blockIdx.y * 32;
  int tx = threadIdx.x, ty = threadIdx.y;
#pragma unroll
  for (int i = 0; i < 4; i++) {
    int k = k0 + ty + i * 8, n = n0 + tx;
    tile[ty + i * 8][tx] = W[(size_t)k * HD + n];
  }
  __syncthreads();
#pragma unroll
  for (int i = 0; i < 4; i++) {
    int n = n0 + ty + i * 8, k = k0 + tx;
    u16 s0, s1;
    split2(tile[tx][ty + i * 8], s0, s1);
    size_t o = (size_t)n * HD + k;
    ((u16*)p0)[o] = s0;
    ((u16*)p1)[o] = s1;
  }
}

// ==== G1 big-tile GEMM: BM=256 x BN=128, K-split-2 (blockIdx.z), 8 waves
// (4M x 2N, wave tile 64x64), BK=32, ring-3 LDS (144 KB), 3-phase schedule
// (round-7 discipline: per phase {ds_read, stage, barrier, lgkmcnt(0),
// setprio, 16 MFMA, setprio, barrier}), counted vmcnt(6) once per tile,
// T2 both-sides swizzle. Buffers: A0 @0, A1 @8192, B0 @16384, B1 @20480.
__global__ __launch_bounds__(512, 2) void k_gemm_big(
    const f16* __restrict__ A0p, const f16* __restrict__ A1p,
    const f16* __restrict__ B0p, const f16* __restrict__ B1p,
    float* __restrict__ P, int ldA, int ldB, int nk) {
  __shared__ __align__(16) u16 lds[3 * 24576];

  const u32 gx = gridDim.x, gy = gridDim.y;
  const u32 nwg = gx * gy * gridDim.z;
  u32 lin = blockIdx.x + gx * (blockIdx.y + gy * blockIdx.z);
  {  // bijective XCD swizzle: the 8 bx-blocks of one (by,bz) share an XCD
    const u32 q = nwg >> 3, r = nwg & 7;
    const u32 xcd = lin & 7, o = lin >> 3;
    lin = (xcd < r ? xcd * (q + 1) : r * (q + 1) + (xcd - r) * q) + o;
  }
  const u32 bz = lin / (gx * gy);
  const u32 rem = lin - bz * gx * gy;
  const u32 by = rem / gx;
  const u32 bx = rem - by * gx;
  const int m0 = by * 256, n0 = bx * 128;
  const size_t kbase = (size_t)bz * KC;

  const u16* __restrict__ A0u = (const u16*)A0p + kbase;
  const u16* __restrict__ A1u = (const u16*)A1p + kbase;
  const u16* __restrict__ B0u = (const u16*)B0p + kbase;
  const u16* __restrict__ B1u = (const u16*)B1p + kbase;
  float* __restrict__ Pz = P + (size_t)bz * NB * HD;

  const int t = threadIdx.x;
  const int lane = t & 63;
  const int wid = t >> 6;
  const int wm = wid >> 1, wn = wid & 1;  // 4M x 2N waves, tile 64x64
  const int l15 = lane & 15, l4 = lane >> 4;

  // staging: A chunks c = t and 512+t (row = c>>2, slot = c&3); B chunk c = t.
  // global col-chunk pre-swizzled: (c&3) ^ ((c>>3)&3)  [identical for c+512]
  const int sgc = (((t & 3) ^ ((t >> 3) & 3)) << 3);
  const size_t gA0 = (size_t)(m0 + (t >> 2)) * ldA + sgc;
  const size_t gA1 = gA0 + (size_t)128 * ldA;
  const size_t gB = (size_t)(n0 + (t >> 2)) * ldB + sgc;
  const int dA0 = t * 8, dB = t * 8;

  // ds_read offsets (u16 units), same XOR swizzle
  int offA[4], offB[4];
#pragma unroll
  for (int mi = 0; mi < 4; mi++) {
    int row = wm * 64 + mi * 16 + l15;
    offA[mi] = row * 32 + ((l4 ^ ((row >> 1) & 3)) << 3);
  }
#pragma unroll
  for (int ni = 0; ni < 4; ni++) {
    int row = wn * 64 + ni * 16 + l15;
    offB[ni] = row * 32 + ((l4 ^ ((row >> 1) & 3)) << 3);
  }

  f32x4 hi[4][4], lo[4][4];
#pragma unroll
  for (int i = 0; i < 4; i++)
#pragma unroll
    for (int j = 0; j < 4; j++) {
      f32x4 z = {0.f, 0.f, 0.f, 0.f};
      hi[i][j] = z;
      lo[i][j] = z;
    }

#define STAGE_A0(Sb, ko)                         \
  gload_lds16(A0u + gA0 + (ko), (Sb) + dA0);     \
  gload_lds16(A0u + gA1 + (ko), (Sb) + 4096 + dA0);
#define STAGE_A1(Sb, ko)                              \
  gload_lds16(A1u + gA0 + (ko), (Sb) + 8192 + dA0);   \
  gload_lds16(A1u + gA1 + (ko), (Sb) + 12288 + dA0);
#define STAGE_B(Sb, ko)                               \
  gload_lds16(B0u + gB + (ko), (Sb) + 16384 + dB);    \
  gload_lds16(B1u + gB + (ko), (Sb) + 20480 + dB);

#define MFMA16(dst, af, bf)                                              \
  _Pragma("unroll") for (int mi = 0; mi < 4; mi++)                       \
      _Pragma("unroll") for (int ni = 0; ni < 4; ni++)                   \
          dst[mi][ni] = __builtin_amdgcn_mfma_f32_16x16x32_f16(          \
              af[mi], bf[ni], dst[mi][ni], 0, 0, 0);

  // prologue: stage tiles 0,1 -> bufs 0,1 (12 loads/thread in flight)
  {
    u16* Sb0 = lds;
    u16* Sb1 = lds + 24576;
    STAGE_A0(Sb0, 0) STAGE_A1(Sb0, 0) STAGE_B(Sb0, 0)
    STAGE_A0(Sb1, 32) STAGE_A1(Sb1, 32) STAGE_B(Sb1, 32)
  }
  asm volatile("s_waitcnt vmcnt(6)" ::: "memory");  // tile 0 resident
  __builtin_amdgcn_s_barrier();
  __builtin_amdgcn_sched_barrier(0);

  for (int tau = 0; tau < nk - 2; ++tau) {
    const u16* Lb = lds + (tau % 3) * 24576;
    u16* Sb = lds + ((tau + 2) % 3) * 24576;
    const size_t ko = (size_t)(tau + 2) * 32;
    f16x8 a0[4], b0[4], xf[4];

    // ---- phase 0: read a0,b0; stage A0(tau+2); hi += a0*b0
#pragma unroll
    for (int mi = 0; mi < 4; mi++) a0[mi] = *(const f16x8*)(Lb + offA[mi]);
#pragma unroll
    for (int ni = 0; ni < 4; ni++)
      b0[ni] = *(const f16x8*)(Lb + 16384 + offB[ni]);
    STAGE_A0(Sb, ko)
    __builtin_amdgcn_s_barrier();
    asm volatile("s_waitcnt lgkmcnt(0)" ::: "memory");
    __builtin_amdgcn_sched_barrier(0);
    __builtin_amdgcn_s_setprio(1);
    MFMA16(hi, a0, b0)
    __builtin_amdgcn_s_setprio(0);
    __builtin_amdgcn_s_barrier();

    // ---- phase 1: read b1; stage A1(tau+2); lo += a0*b1
#pragma unroll
    for (int ni = 0; ni < 4; ni++)
      xf[ni] = *(const f16x8*)(Lb + 20480 + offB[ni]);
    STAGE_A1(Sb, ko)
    __builtin_amdgcn_s_barrier();
    asm volatile("s_waitcnt lgkmcnt(0)" ::: "memory");
    __builtin_amdgcn_sched_barrier(0);
    __builtin_amdgcn_s_setprio(1);
    MFMA16(lo, a0, xf)
    __builtin_amdgcn_s_setprio(0);
    __builtin_amdgcn_s_barrier();

    // ---- phase 2: read a1; stage B(tau+2); vmcnt; lo += a1*b0
#pragma unroll
    for (int mi = 0; mi < 4; mi++)
      xf[mi] = *(const f16x8*)(Lb + 8192 + offA[mi]);
    STAGE_B(Sb, ko)
    asm volatile("s_waitcnt vmcnt(6)" ::: "memory");
    __builtin_amdgcn_s_barrier();
    asm volatile("s_waitcnt lgkmcnt(0)" ::: "memory");
    __builtin_amdgcn_sched_barrier(0);
    __builtin_amdgcn_s_setprio(1);
    MFMA16(lo, xf, b0)
    __builtin_amdgcn_s_setprio(0);
    __builtin_amdgcn_s_barrier();
  }
  // tail: drain everything once, then compute last 2 tiles (all resident)
  asm volatile("s_waitcnt vmcnt(0)" ::: "memory");
  __builtin_amdgcn_s_barrier();
  __builtin_amdgcn_sched_barrier(0);
#pragma unroll 1
  for (int tau = nk - 2; tau < nk; ++tau) {
    const u16* Lb = lds + (tau % 3) * 24576;
    f16x8 a0[4], b0[4], xf[4];
#pragma unroll
    for (int mi = 0; mi < 4; mi++) a0[mi] = *(const f16x8*)(Lb + offA[mi]);
#pragma unroll
    for (int ni = 0; ni < 4; ni++)
      b0[ni] = *(const f16x8*)(Lb + 16384 + offB[ni]);
    MFMA16(hi, a0, b0)
#pragma unroll
    for (int ni = 0; ni < 4; ni++)
      xf[ni] = *(const f16x8*)(Lb + 20480 + offB[ni]);
    MFMA16(lo, a0, xf)
#pragma unroll
    for (int mi = 0; mi < 4; mi++)
      xf[mi] = *(const f16x8*)(Lb + 8192 + offA[mi]);
    MFMA16(lo, xf, b0)
  }
#undef STAGE_A0
#undef STAGE_A1
#undef STAGE_B
#undef MFMA16

  // write raw f32 combined partials to this half's P
  const int rowb = m0 + wm * 64 + l4 * 4;
  const int colb = n0 + wn * 64 + l15;
#pragma unroll
  for (int mi = 0; mi < 4; mi++) {
#pragma unroll
    for (int ni = 0; ni < 4; ni++) {
      const int col = colb + ni * 16;
#pragma unroll
      for (int r = 0; r < 4; r++) {
        const int row = rowb + mi * 16 + r;
        Pz[(size_t)row * HD + col] = hi[mi][ni][r] + lo[mi][ni][r] * RSC;
      }
    }
  }
}

// ---- G1 epilogue: y = P0 + P1, BN + ReLU -> hF + f16 planes
__global__ __launch_bounds__(256) void k_epi1(
    const float* __restrict__ P0, const float* __restrict__ P1,
    const float* __restrict__ bias, const float* __restrict__ gam,
    const float* __restrict__ bet, const float* __restrict__ mu,
    const float* __restrict__ var, float* __restrict__ hF,
    f16* __restrict__ h0, f16* __restrict__ h1) {
  const u32 i4 = (blockIdx.x * 256u + threadIdx.x) * 4u;
  const u32 col0 = i4 & (HD - 1);
  f32x4 a = *(const f32x4*)(P0 + i4);
  f32x4 b = *(const f32x4*)(P1 + i4);
  f32x4 y;
  u16x4 o0, o1;
#pragma unroll
  for (int e = 0; e < 4; e++) {
    const u32 c = col0 + e;
    float sc = gam[c] * rsqrtf(var[c] + BN_EPS);
    float v = ((a[e] + b[e]) + bias[c] - mu[c]) * sc + bet[c];
    v = fmaxf(v, 0.f);
    y[e] = v;
    u16 s0, s1;
    split2(v, s0, s1);
    o0[e] = s0;
    o1[e] = s1;
  }
  *(f32x4*)(hF + i4) = y;
  *(u16x4*)((u16*)h0 + i4) = o0;
  *(u16x4*)((u16*)h1 + i4) = o1;
}

// ==== fused 128x128 GEMM (mids/G6): 8 waves (4M x 2N, wave tile 32x64),
// BK=32, ring-4 LDS, 3-phase schedule, counted vmcnt(8) + peeled tail,
// T2 swizzle, T5. Buffer layout: A0 @0, A1 @4096, B0 @8192, B1 @12288.
// EPI: 1=mid(BN,ReLU -> planes) 2=res(BN,ReLU,+hF -> hF+planes)
//      3=res(-> planes only) 4=out(bias -> oF)
template <int EPI>
__global__ __launch_bounds__(512, 2) void k_gemm_f(
    const f16* __restrict__ A0p, const f16* __restrict__ A1p,
    const f16* __restrict__ B0p, const f16* __restrict__ B1p,
    const float* __restrict__ bias, const float* __restrict__ gam,
    const float* __restrict__ bet, const float* __restrict__ mu,
    const float* __restrict__ var, const float* __restrict__ resF,
    float* __restrict__ hFout, f16* __restrict__ pl0, f16* __restrict__ pl1,
    float* __restrict__ oF, int ldA, int ldB, int nk, int ldout) {
  __shared__ __align__(16) u16 lds[4 * 16384];

  const u32 gx = gridDim.x, gy = gridDim.y;
  const u32 nwg = gx * gy;
  u32 lin = blockIdx.x + gx * blockIdx.y;
  {
    const u32 q = nwg >> 3, r = nwg & 7;
    const u32 xcd = lin & 7, o = lin >> 3;
    lin = (xcd < r ? xcd * (q + 1) : r * (q + 1) + (xcd - r) * q) + o;
  }
  const u32 by = lin / gx;
  const u32 bx = lin - by * gx;
  const int m0 = by * 128, n0 = bx * 128;

  const u16* __restrict__ A0u = (const u16*)A0p;
  const u16* __restrict__ A1u = (const u16*)A1p;
  const u16* __restrict__ B0u = (const u16*)B0p;
  const u16* __restrict__ B1u = (const u16*)B1p;

  const int t = threadIdx.x;
  const int lane = t & 63;
  const int wid = t >> 6;
  const int wm = wid >> 1, wn = wid & 1;  // 4M x 2N, wave tile 32x64
  const int l15 = lane & 15, l4 = lane >> 4;

  const int srow = t >> 2, sj = t & 3;
  const int sgc = ((sj ^ ((srow >> 1) & 3)) << 3);
  const size_t gA = (size_t)(m0 + srow) * ldA + sgc;
  const size_t gB = (size_t)(n0 + srow) * ldB + sgc;
  const int d0 = t * 8;

  int offA[2], offB[4];
#pragma unroll
  for (int mi = 0; mi < 2; mi++) {
    int row = wm * 32 + mi * 16 + l15;
    offA[mi] = row * 32 + ((l4 ^ ((row >> 1) & 3)) << 3);
  }
#pragma unroll
  for (int ni = 0; ni < 4; ni++) {
    int row = wn * 64 + ni * 16 + l15;
    offB[ni] = row * 32 + ((l4 ^ ((row >> 1) & 3)) << 3);
  }

  f32x4 hi[2][4], lo[2][4];
#pragma unroll
  for (int i = 0; i < 2; i++)
#pragma unroll
    for (int j = 0; j < 4; j++) {
      f32x4 z = {0.f, 0.f, 0.f, 0.f};
      hi[i][j] = z;
      lo[i][j] = z;
    }

#define STG_A0(Sb, ko) gload_lds16(A0u + gA + (ko), (Sb) + d0);
#define STG_A1(Sb, ko) gload_lds16(A1u + gA + (ko), (Sb) + 4096 + d0);
#define STG_B(Sb, ko)                               \
  gload_lds16(B0u + gB + (ko), (Sb) + 8192 + d0);   \
  gload_lds16(B1u + gB + (ko), (Sb) + 12288 + d0);
#define MFMA8(dst, af, bf)                                               \
  _Pragma("unroll") for (int mi = 0; mi < 2; mi++)                       \
      _Pragma("unroll") for (int ni = 0; ni < 4; ni++)                   \
          dst[mi][ni] = __builtin_amdgcn_mfma_f32_16x16x32_f16(          \
              af[mi], bf[ni], dst[mi][ni], 0, 0, 0);

  // prologue: stage tiles 0,1,2 -> bufs 0,1,2
  {
    u16* S0 = lds;
    u16* S1 = lds + 16384;
    u16* S2 = lds + 32768;
    STG_A0(S0, 0) STG_A1(S0, 0) STG_B(S0, 0)
    STG_A0(S1, 32) STG_A1(S1, 32) STG_B(S1, 32)
    STG_A0(S2, 64) STG_A1(S2, 64) STG_B(S2, 64)
  }
  asm volatile("s_waitcnt vmcnt(8)" ::: "memory");
  __builtin_amdgcn_s_barrier();
  __builtin_amdgcn_sched_barrier(0);

  for (int tau = 0; tau < nk - 3; ++tau) {
    const u16* Lb = lds + (tau & 3) * 16384;
    u16* Sb = lds + ((tau + 3) & 3) * 16384;
    const size_t ko = (size_t)(tau + 3) * 32;
    f16x8 a0[2], b0[4], xf[4];

    // phase 0: read a0,b0; stage A0; hi += a0*b0
#pragma unroll
    for (int mi = 0; mi < 2; mi++) a0[mi] = *(const f16x8*)(Lb + offA[mi]);
#pragma unroll
    for (int ni = 0; ni < 4; ni++)
      b0[ni] = *(const f16x8*)(Lb + 8192 + offB[ni]);
    STG_A0(Sb, ko)
    __builtin_amdgcn_s_barrier();
    asm volatile("s_waitcnt lgkmcnt(0)" ::: "memory");
    __builtin_amdgcn_sched_barrier(0);
    __builtin_amdgcn_s_setprio(1);
    MFMA8(hi, a0, b0)
    __builtin_amdgcn_s_setprio(0);
    __builtin_amdgcn_s_barrier();

    // phase 1: read b1; stage A1; lo += a0*b1
#pragma unroll
    for (int ni = 0; ni < 4; ni++)
      xf[ni] = *(const f16x8*)(Lb + 12288 + offB[ni]);
    STG_A1(Sb, ko)
    __builtin_amdgcn_s_barrier();
    asm volatile("s_waitcnt lgkmcnt(0)" ::: "memory");
    __builtin_amdgcn_sched_barrier(0);
    __builtin_amdgcn_s_setprio(1);
    MFMA8(lo, a0, xf)
    __builtin_amdgcn_s_setprio(0);
    __builtin_amdgcn_s_barrier();

    // phase 2: read a1; stage B; vmcnt; lo += a1*b0
#pragma unroll
    for (int mi = 0; mi < 2; mi++)
      xf[mi] = *(const f16x8*)(Lb + 4096 + offA[mi]);
    STG_B(Sb, ko)
    asm volatile("s_waitcnt vmcnt(8)" ::: "memory");
    __builtin_amdgcn_s_barrier();
    asm volatile("s_waitcnt lgkmcnt(0)" ::: "memory");
    __builtin_amdgcn_sched_barrier(0);
    __builtin_amdgcn_s_setprio(1);
    MFMA8(lo, xf, b0)
    __builtin_amdgcn_s_setprio(0);
    __builtin_amdgcn_s_barrier();
  }
  asm volatile("s_waitcnt vmcnt(0)" ::: "memory");
  __builtin_amdgcn_s_barrier();
  __builtin_amdgcn_sched_barrier(0);
#pragma unroll 1
  for (int tau = nk - 3; tau < nk; ++tau) {
    const u16* Lb = lds + (tau & 3) * 16384;
    f16x8 a0[2], b0[4], xf[4];
#pragma unroll
    for (int mi = 0; mi < 2; mi++) a0[mi] = *(const f16x8*)(Lb + offA[mi]);
#pragma unroll
    for (int ni = 0; ni < 4; ni++)
      b0[ni] = *(const f16x8*)(Lb + 8192 + offB[ni]);
    MFMA8(hi, a0, b0)
#pragma unroll
    for (int ni = 0; ni < 4; ni++)
      xf[ni] = *(const f16x8*)(Lb + 12288 + offB[ni]);
    MFMA8(lo, a0, xf)
#pragma unroll
    for (int mi = 0; mi < 2; mi++)
      xf[mi] = *(const f16x8*)(Lb + 4096 + offA[mi]);
    MFMA8(lo, xf, b0)
  }
#undef STG_A0
#undef STG_A1
#undef STG_B
#undef MFMA8

  const int rowb = m0 + wm * 32 + l4 * 4;
  const int colb = n0 + wn * 64 + l15;
#pragma unroll
  for (int ni = 0; ni < 4; ni++) {
    const int col = colb + ni * 16;
    float sc = 1.f, pb = 0.f;
    if (EPI == 4) {
      pb = (col < OD) ? bias[col] : 0.f;
    } else {
      sc = gam[col] * rsqrtf(var[col] + BN_EPS);
      pb = (bias[col] - mu[col]) * sc + bet[col];
    }
#pragma unroll
    for (int mi = 0; mi < 2; mi++) {
#pragma unroll
      for (int r = 0; r < 4; r++) {
        const int row = rowb + mi * 16 + r;
        float s = hi[mi][ni][r] + lo[mi][ni][r] * RSC;
        if (EPI == 4) {
          oF[(size_t)row * ldout + col] = s + pb;
          continue;
        }
        float v = s * sc + pb;
        if (EPI == 2 || EPI == 3) v += resF[(size_t)row * HD + col];
        v = fmaxf(v, 0.f);
        if (EPI == 2) hFout[(size_t)row * HD + col] = v;
        u16 s0, s1;
        split2(v, s0, s1);
        size_t o = (size_t)row * HD + col;
        ((u16*)pl0)[o] = s0;
        ((u16*)pl1)[o] = s1;
      }
    }
  }
}

// ---- polar factor of each 3x3 block (scaled Newton) * sign(det); oF ld=256
__global__ __launch_bounds__(256) void k_polar(const float* __restrict__ oF,
                                               float* __restrict__ R) {
  int g = blockIdx.x * 256 + threadIdx.x;
  if (g >= NB * 24) return;
  int b = g / 24, j = g - b * 24;
  const float* p = oF + (size_t)b * OPAD + j * 9;
  float xv[9];
#pragma unroll
  for (int e = 0; e < 9; e++) xv[e] = p[e];
#pragma unroll 1
  for (int it = 0; it < 18; it++) {
    float c0 = xv[4] * xv[8] - xv[5] * xv[7];
    float c1 = xv[5] * xv[6] - xv[3] * xv[8];
    float c2 = xv[3] * xv[7] - xv[4] * xv[6];
    float c3 = xv[2] * xv[7] - xv[1] * xv[8];
    float c4 = xv[0] * xv[8] - xv[2] * xv[6];
    float c5 = xv[1] * xv[6] - xv[0] * xv[7];
    float c6 = xv[1] * xv[5] - xv[2] * xv[4];
    float c7 = xv[2] * xv[3] - xv[0] * xv[5];
    float c8 = xv[0] * xv[4] - xv[1] * xv[3];
    float det = xv[0] * c0 + xv[1] * c1 + xv[2] * c2;
    if (fabsf(det) < 1e-30f) break;
    float inv = 1.f / det;
    float y0 = c0 * inv, y1 = c1 * inv, y2 = c2 * inv;
    float y3 = c3 * inv, y4 = c4 * inv, y5 = c5 * inv;
    float y6 = c6 * inv, y7 = c7 * inv, y8 = c8 * inv;
    float gmm = 1.f;
    if (it < 8) {
      float nx = xv[0]*xv[0]+xv[1]*xv[1]+xv[2]*xv[2]+xv[3]*xv[3]+xv[4]*xv[4]
               + xv[5]*xv[5]+xv[6]*xv[6]+xv[7]*xv[7]+xv[8]*xv[8];
      float ny = y0*y0+y1*y1+y2*y2+y3*y3+y4*y4+y5*y5+y6*y6+y7*y7+y8*y8;
      gmm = sqrtf(sqrtf(ny / nx));
    }
    float a0 = 0.5f * gmm, a1 = 0.5f / gmm;
    xv[0] = a0 * xv[0] + a1 * y0; xv[1] = a0 * xv[1] + a1 * y1;
    xv[2] = a0 * xv[2] + a1 * y2; xv[3] = a0 * xv[3] + a1 * y3;
    xv[4] = a0 * xv[4] + a1 * y4; xv[5] = a0 * xv[5] + a1 * y5;
    xv[6] = a0 * xv[6] + a1 * y6; xv[7] = a0 * xv[7] + a1 * y7;
    xv[8] = a0 * xv[8] + a1 * y8;
  }
  float dfin = xv[0] * (xv[4] * xv[8] - xv[5] * xv[7])
             + xv[1] * (xv[5] * xv[6] - xv[3] * xv[8])
             + xv[2] * (xv[3] * xv[7] - xv[4] * xv[6]);
  float s = (dfin > 0.f) ? 1.f : -1.f;
  float* q = R + (size_t)g * 9;
#pragma unroll
  for (int e = 0; e < 9; e++) q[e] = s * xv[e];
}

__global__ __launch_bounds__(256) void k_betas(const float* __restrict__ oF,
                                               float* __restrict__ dst) {
  int i = blockIdx.x * 256 + threadIdx.x;
  if (i >= NB * 10) return;
  int b = i / 10, j = i - b * 10;
  dst[i] = oF[(size_t)b * OPAD + 216 + j];
}

extern "C" void kernel_launch(void* const* d_in, const int* in_sizes, int n_in,
                              void* d_out, int out_size, void* d_ws, size_t ws_size,
                              hipStream_t stream) {
  const float* x   = (const float*)d_in[0];
  const float* W1  = (const float*)d_in[1];
  const float* b1  = (const float*)d_in[2];
  const float* g1  = (const float*)d_in[3];
  const float* be1 = (const float*)d_in[4];
  const float* m1  = (const float*)d_in[5];
  const float* v1  = (const float*)d_in[6];
  const float* Wa  = (const float*)d_in[7];
  const float* ba  = (const float*)d_in[8];
  const float* ga  = (const float*)d_in[9];
  const float* bea = (const float*)d_in[10];
  const float* ma  = (const float*)d_in[11];
  const float* va  = (const float*)d_in[12];
  const float* Wb  = (const float*)d_in[13];
  const float* bb  = (const float*)d_in[14];
  const float* gb  = (const float*)d_in[15];
  const float* beb = (const float*)d_in[16];
  const float* mb  = (const float*)d_in[17];
  const float* vb  = (const float*)d_in[18];
  const float* Wc  = (const float*)d_in[19];
  const float* bc  = (const float*)d_in[20];
  const float* gc  = (const float*)d_in[21];
  const float* bec = (const float*)d_in[22];
  const float* mc  = (const float*)d_in[23];
  const float* vc  = (const float*)d_in[24];
  const float* Wd  = (const float*)d_in[25];
  const float* bd  = (const float*)d_in[26];
  const float* gd  = (const float*)d_in[27];
  const float* bed = (const float*)d_in[28];
  const float* md  = (const float*)d_in[29];
  const float* vd  = (const float*)d_in[30];
  const float* Wf  = (const float*)d_in[31];
  const float* bf  = (const float*)d_in[32];
  (void)in_sizes; (void)n_in; (void)out_size; (void)ws_size;

  char* ws = (char*)d_ws;
  size_t off = 0;
  auto alloc = [&](size_t bytes) -> void* {
    void* p = ws + off;
    off += (bytes + 255) & ~(size_t)255;
    return p;
  };
  f16* xp0 = (f16*)alloc((size_t)NB * DPAD * 2);        // 84.9 MB
  f16* xp1 = (f16*)alloc((size_t)NB * DPAD * 2);        // 84.9 MB
  f16* w1p0 = (f16*)alloc((size_t)HD * DPAD * 2);       // 21.2 MB
  f16* w1p1 = (f16*)alloc((size_t)HD * DPAD * 2);
  f16* wap0 = (f16*)alloc((size_t)HD * HD * 2);
  f16* wap1 = (f16*)alloc((size_t)HD * HD * 2);
  f16* wbp0 = (f16*)alloc((size_t)HD * HD * 2);
  f16* wbp1 = (f16*)alloc((size_t)HD * HD * 2);
  f16* wcp0 = (f16*)alloc((size_t)HD * HD * 2);
  f16* wcp1 = (f16*)alloc((size_t)HD * HD * 2);
  f16* wdp0 = (f16*)alloc((size_t)HD * HD * 2);
  f16* wdp1 = (f16*)alloc((size_t)HD * HD * 2);
  f16* wfp0 = (f16*)alloc((size_t)OPAD * HD * 2);
  f16* wfp1 = (f16*)alloc((size_t)OPAD * HD * 2);
  float* P = (float*)alloc((size_t)2 * NB * HD * 4);    // 33.6 MB (2 halves)
  // activations alias the xp0 region (dead after the G1 GEMM dispatch):
  f16* h0 = (f16*)xp0;
  f16* h1 = h0 + (size_t)NB * HD;
  f16* t0 = h1 + (size_t)NB * HD;
  f16* t1 = t0 + (size_t)NB * HD;
  float* hF = (float*)(t1 + (size_t)NB * HD);
  float* oF = hF + (size_t)NB * HD;                     // ends ~54.5 MB < 84.9

  k_split_x<<<NB * DPAD / 4 / 256, 256, 0, stream>>>(x, xp0, xp1);
  dim3 tb(32, 8);
  k_split_w<<<dim3(DPAD / 32, HD / 32), tb, 0, stream>>>(W1, w1p0, w1p1, DIN, HD, DPAD);
  WPack wp;
  wp.W[0] = Wa; wp.W[1] = Wb; wp.W[2] = Wc; wp.W[3] = Wd;
  wp.p0[0] = wap0; wp.p0[1] = wbp0; wp.p0[2] = wcp0; wp.p0[3] = wdp0;
  wp.p1[0] = wap1; wp.p1[1] = wbp1; wp.p1[2] = wcp1; wp.p1[3] = wdp1;
  k_split_w4<<<dim3(HD / 32, HD / 32, 4), tb, 0, stream>>>(wp);
  k_split_w<<<dim3(HD / 32, OPAD / 32), tb, 0, stream>>>(Wf, wfp0, wfp1, HD, OD, HD);

  dim3 g1g(HD / 128, NB / 256, 2);  // (8, 16, 2) = 256 blocks
  dim3 gg(HD / 128, NB / 128);      // (8, 32) = 256 blocks
  dim3 gf(OPAD / 128, NB / 128);    // (2, 32) = 64 blocks

  // G1 GEMM: K-split halves -> P0, P1
  k_gemm_big<<<g1g, 512, 0, stream>>>(xp0, xp1, w1p0, w1p1, P, DPAD, DPAD,
                                      KC / 32);
  // G1 epilogue: h = relu(bn(P0+P1+b1)) -> hF + h planes
  k_epi1<<<NB * HD / 4 / 256, 256, 0, stream>>>(P, P + (size_t)NB * HD, b1, g1,
                                                be1, m1, v1, hF, h0, h1);
  // G2: t = relu(bn(h@Wa+ba)) -> t planes
  k_gemm_f<1><<<gg, 512, 0, stream>>>(
      h0, h1, wap0, wap1, ba, ga, bea, ma, va, nullptr, nullptr, t0, t1,
      nullptr, HD, HD, HD / 32, HD);
  // G3: h = relu(h + bn(t@Wb+bb)) -> hF + h planes (in-place hF safe)
  k_gemm_f<2><<<gg, 512, 0, stream>>>(
      t0, t1, wbp0, wbp1, bb, gb, beb, mb, vb, hF, hF, h0, h1, nullptr, HD,
      HD, HD / 32, HD);
  // G4: t = relu(bn(h@Wc+bc)) -> t planes
  k_gemm_f<1><<<gg, 512, 0, stream>>>(
      h0, h1, wcp0, wcp1, bc, gc, bec, mc, vc, nullptr, nullptr, t0, t1,
      nullptr, HD, HD, HD / 32, HD);
  // G5: h = relu(h + bn(t@Wd+bd)) -> h planes only
  k_gemm_f<3><<<gg, 512, 0, stream>>>(
      t0, t1, wdp0, wdp1, bd, gd, bed, md, vd, hF, nullptr, h0, h1, nullptr,
      HD, HD, HD / 32, HD);
  // G6: out = h@Wf+bf -> oF f32 [4096][256]
  k_gemm_f<4><<<gf, 512, 0, stream>>>(
      h0, h1, wfp0, wfp1, bf, nullptr, nullptr, nullptr, nullptr, nullptr,
      nullptr, nullptr, nullptr, oF, HD, HD, HD / 32, OPAD);

  float* Rout = (float*)d_out;
  k_polar<<<(NB * 24 + 255) / 256, 256, 0, stream>>>(oF, Rout);
  k_betas<<<(NB * 10 + 255) / 256, 256, 0, stream>>>(oF, Rout + (size_t)NB * 216);
}